// Round 10
// baseline (160.243 us; speedup 1.0000x reference)
//
#include <hip/hip_runtime.h>
#include <math.h>

#define NN 2048
#define HID 128
#define HID2 64
#define NP ((NN*(NN-1))/2)   // 2096128

typedef __bf16 bf16x8 __attribute__((ext_vector_type(8)));
typedef float  f32x4  __attribute__((ext_vector_type(4)));
typedef float  f32x16 __attribute__((ext_vector_type(16)));

// Kernel 1: per node row: h = relu(X@Wt+bt); a = h@W1top + b1; b = h@W1bot.
// Emits Abf (bf16 row-major), Bp (bf16 packed for 32x32x16 B-operand), and
// per-row stats sa/sb from the bf16-ROUNDED values.
__global__ __launch_bounds__(128) void precompute_AB(
    const float* __restrict__ X, const float* __restrict__ Wt, const float* __restrict__ bt,
    const float* __restrict__ W1, const float* __restrict__ b1,
    __bf16* __restrict__ Abf, __bf16* __restrict__ Bp,
    float2* __restrict__ sa, float2* __restrict__ sb)
{
    __shared__ float x_s[HID];
    __shared__ float h_s[HID];
    __shared__ float red[2][4];
    const int row = blockIdx.x;
    const int c = threadIdx.x;
    x_s[c] = X[row*HID + c];
    __syncthreads();
    float hc = bt[c];
    #pragma unroll 8
    for (int k = 0; k < HID; ++k) hc = fmaf(x_s[k], Wt[k*HID + c], hc);
    h_s[c] = fmaxf(hc, 0.f);
    __syncthreads();
    float a = b1[c];
    float bsum = 0.f;
    #pragma unroll 8
    for (int k = 0; k < HID; ++k) {
        float hk = h_s[k];
        a    = fmaf(hk, W1[k*HID + c], a);
        bsum = fmaf(hk, W1[(HID + k)*HID + c], bsum);
    }
    const __bf16 ab = (__bf16)a;
    const __bf16 bb = (__bf16)bsum;
    Abf[row*HID + c] = ab;
    // 32x32x16 B-operand packing: lane = (row&31) + ((c>>3)&1)*32, frag ks = c>>4, e = c&7
    {
        const size_t idx = ((((size_t)(row >> 5))*8 + (c >> 4))*64
                           + (row & 31) + ((c >> 3) & 1)*32)*8 + (c & 7);
        Bp[idx] = bb;
    }
    const float ar = (float)ab;
    const float br = (float)bb;
    float r0 = ar, r1 = ar*ar, r2 = br, r3 = br*br;
    #pragma unroll
    for (int m = 1; m <= 32; m <<= 1) {
        r0 += __shfl_xor(r0, m); r1 += __shfl_xor(r1, m);
        r2 += __shfl_xor(r2, m); r3 += __shfl_xor(r3, m);
    }
    if ((c & 63) == 0) {
        red[c >> 6][0] = r0; red[c >> 6][1] = r1; red[c >> 6][2] = r2; red[c >> 6][3] = r3;
    }
    __syncthreads();
    if (c == 0) {
        sa[row] = make_float2(red[0][0] + red[1][0], red[0][1] + red[1][1]);
        sb[row] = make_float2(red[0][2] + red[1][2], red[0][3] + red[1][3]);
    }
}

// Kernel 1b: pack W2 (fp32 [128][64]) into 32x32x16 A-operand fragments.
// frag f = mt*8 + ks; lane l; elem e  <-  W2[ks*16 + (l>>5)*8 + e][mt*32 + (l&31)]
__global__ __launch_bounds__(256) void pack_W2(const float* __restrict__ W2,
                                               __bf16* __restrict__ W2p)
{
    const int t = threadIdx.x;
    for (int fs = t; fs < 16*64; fs += 256) {
        const int frag = fs >> 6, lane = fs & 63;
        const int mt = frag >> 3, ks = frag & 7;
        const int kbase = ks*16 + (lane >> 5)*8;
        const int col   = mt*32 + (lane & 31);
        #pragma unroll
        for (int e = 0; e < 8; ++e)
            W2p[fs*8 + e] = (__bf16)W2[(kbase + e)*HID2 + col];
    }
}

// Kernel 1c: pair_index is a pure function of indices.
__global__ __launch_bounds__(256) void fill_pi(float* __restrict__ pi)
{
    const int i = blockIdx.x;
    const size_t off = (size_t)i*(NN-1) - (size_t)i*(i-1)/2;
    const int cnt = NN - 1 - i;
    for (int t = threadIdx.x; t < cnt; t += 256) {
        pi[off + t]      = (float)i;
        pi[NP + off + t] = (float)(i + 1 + t);
    }
}

// Kernel 2: 256 threads (4 waves); wave = 64 j's as 2 subs of 32 pairs,
// 32x32x16 MFMA. W2 in LDS (32 b128 reads/wave, half of the 16x16 path).
__global__ __launch_bounds__(256, 3) void pairs_mfma(
    const __bf16* __restrict__ Abf, const __bf16* __restrict__ Bp,
    const float2* __restrict__ sa, const float2* __restrict__ sb,
    const float* __restrict__ ln_g, const float* __restrict__ ln_b,
    const __bf16* __restrict__ W2p, const float* __restrict__ b2,
    const float* __restrict__ W3, const float* __restrict__ b3,
    float* __restrict__ out)
{
    __shared__ bf16x8 w2s[16*64];            // 16 KB: all W2 fragments

    {
        const bf16x8* __restrict__ W2v = (const bf16x8*)W2p;
        #pragma unroll
        for (int t = 0; t < 4; ++t)
            w2s[t*256 + threadIdx.x] = W2v[t*256 + threadIdx.x];
    }

    // decode linear tile id -> (i, jb) over upper-triangular 256x256 tiles
    int t = blockIdx.x;
    int q = 0, base = 0;
    while (q < 7 && t >= base + 256*(8 - q)) { base += 256*(8 - q); ++q; }
    const int idx = t - base;
    const int den = 8 - q;
    const int i  = (q << 8) + idx / den;
    const int jb = q + idx % den;

    __syncthreads();

    const int w    = threadIdx.x >> 6;
    const int lane = threadIdx.x & 63;
    const int jw0  = (jb << 8) + (w << 6);       // this wave's 64 j's
    if (jw0 + 63 < i) return;                    // keep the diag wave alive

    const int p32 = lane & 31;
    const int h32 = lane >> 5;                   // k-granule half
    const int h8  = h32*8;

    // A slices for dot (broadcast over M) and zn source: k = ks*16 + h8 + e
    bf16x8 abf[8];
    #pragma unroll
    for (int ks = 0; ks < 8; ++ks)
        abf[ks] = *(const bf16x8*)(Abf + (size_t)i*HID + ks*16 + h8);
    const float2 sav = sa[i];

    const bf16x8* __restrict__ Bpv = (const bf16x8*)Bp;

    float parts[2] = {0.f, 0.f};

    #pragma unroll
    for (int s = 0; s < 2; ++s) {
        const int j32 = jw0 + s*32;
        if (j32 + 31 < i) continue;              // sub fully below diagonal

        // B fragments for these 32 pairs (coalesced 16B/lane, L2)
        bf16x8 bfr[8];
        const size_t fb = ((size_t)(j32 >> 5))*8;
        #pragma unroll
        for (int ks = 0; ks < 8; ++ks) bfr[ks] = Bpv[(fb + ks)*64 + lane];

        // dot(A[i], B[j_p]) for all 32 pairs via broadcast-A 32x32 MFMA
        f32x16 dacc = (f32x16)(0.f);
        #pragma unroll
        for (int ks = 0; ks < 8; ++ks)
            dacc = __builtin_amdgcn_mfma_f32_32x32x16_bf16(abf[ks], bfr[ks], dacc, 0, 0, 0);

        // O(1) LN stats for this lane's pair (all D rows equal; take reg 0)
        const float2 sbv = sb[j32 + p32];
        const float mu   = (sav.x + sbv.x) * (1.f/HID);
        const float ez2  = (sav.y + sbv.y + 2.f*dacc[0]) * (1.f/HID);
        const float rstd = rsqrtf(ez2 - mu*mu + 1e-5f);
        const float v    = -mu * rstd;

        // per-ks: build af (8 zn elems) then 2 MFMAs (W2 from LDS)
        f32x16 acc0 = (f32x16)(0.f);
        f32x16 acc1 = (f32x16)(0.f);
        #pragma unroll
        for (int ks = 0; ks < 8; ++ks) {
            const int kb = ks*16 + h8;
            f32x4 g0 = *(const f32x4*)(ln_g + kb);
            f32x4 g1 = *(const f32x4*)(ln_g + kb + 4);
            f32x4 l0 = *(const f32x4*)(ln_b + kb);
            f32x4 l1 = *(const f32x4*)(ln_b + kb + 4);
            bf16x8 af;
            #pragma unroll
            for (int e = 0; e < 4; ++e) {
                float z0 = (float)abf[ks][e]   + (float)bfr[ks][e];
                float z1 = (float)abf[ks][4+e] + (float)bfr[ks][4+e];
                float q0 = fmaf(rstd, z0, v);
                float q1 = fmaf(rstd, z1, v);
                af[e]   = (__bf16)fmaxf(fmaf(g0[e], q0, l0[e]), 0.f);
                af[4+e] = (__bf16)fmaxf(fmaf(g1[e], q1, l1[e]), 0.f);
            }
            acc0 = __builtin_amdgcn_mfma_f32_32x32x16_bf16(w2s[ks*64 + lane],      af, acc0, 0, 0, 0);
            acc1 = __builtin_amdgcn_mfma_f32_32x32x16_bf16(w2s[(8+ks)*64 + lane],  af, acc1, 0, 0, 0);
        }

        // epilogue: lane holds pair p32; channels ch = mt*32 + rg*8 + 4*h32 + r
        float part = 0.f;
        #pragma unroll
        for (int rg = 0; rg < 4; ++rg) {
            f32x4 b2v0 = *(const f32x4*)(b2 + rg*8 + 4*h32);
            f32x4 w3v0 = *(const f32x4*)(W3 + rg*8 + 4*h32);
            f32x4 b2v1 = *(const f32x4*)(b2 + 32 + rg*8 + 4*h32);
            f32x4 w3v1 = *(const f32x4*)(W3 + 32 + rg*8 + 4*h32);
            #pragma unroll
            for (int r = 0; r < 4; ++r) {
                part = fmaf(fmaxf(acc0[rg*4 + r] + b2v0[r], 0.f), w3v0[r], part);
                part = fmaf(fmaxf(acc1[rg*4 + r] + b2v1[r], 0.f), w3v1[r], part);
            }
        }
        part += __shfl_xor(part, 32);            // sum the two channel halves
        parts[s] = part;                         // full logit-partial for pair p32
    }

    // epilogue, all 64 lanes: lane handles pair j = jw0 + lane
    const float x = (h32 == 0) ? parts[0] : parts[1];

    float* probs = out;
    float* adj   = out + 3*(size_t)NP;
    const int j = jw0 + lane;
    if (j == i) {
        adj[(size_t)i*NN + i] = 0.f;
    } else if (j > i) {
        const float pr = 1.f / (1.f + __expf(-(x + b3[0])));
        const int kpair = i*(NN-1) - (i*(i-1))/2 + (j - i - 1);
        probs[kpair] = pr;
        adj[(size_t)i*NN + j] = pr;
        adj[(size_t)j*NN + i] = pr;
    }
}

extern "C" void kernel_launch(void* const* d_in, const int* in_sizes, int n_in,
                              void* d_out, int out_size, void* d_ws, size_t ws_size,
                              hipStream_t stream) {
    const float* X    = (const float*)d_in[0];
    const float* Wt   = (const float*)d_in[1];
    const float* bt   = (const float*)d_in[2];
    const float* W1   = (const float*)d_in[3];
    const float* b1   = (const float*)d_in[4];
    const float* ln_g = (const float*)d_in[5];
    const float* ln_b = (const float*)d_in[6];
    const float* W2   = (const float*)d_in[7];
    const float* b2   = (const float*)d_in[8];
    const float* W3   = (const float*)d_in[9];
    const float* b3   = (const float*)d_in[10];
    float* out = (float*)d_out;

    float2* sa  = (float2*)d_ws;                       // 16KB
    float2* sb  = sa + NN;                             // 16KB
    __bf16* Abf = (__bf16*)(sb + NN);                  // 512KB
    __bf16* Bp  = Abf + (size_t)NN * HID;              // 512KB (32x32 packed)
    __bf16* W2p = Bp  + (size_t)NN * HID;              // 16KB

    precompute_AB<<<NN, HID, 0, stream>>>(X, Wt, bt, W1, b1, Abf, Bp, sa, sb);
    pack_W2<<<1, 256, 0, stream>>>(W2, W2p);
    fill_pi<<<NN-1, 256, 0, stream>>>(out + NP);

    const int nblk = 256 * 36;
    pairs_mfma<<<nblk, 256, 0, stream>>>(Abf, Bp, sa, sb, ln_g, ln_b, W2p, b2, W3, b3, out);
}

// Round 12
// 101.915 us; speedup vs baseline: 1.5723x; 1.5723x over previous
//
#include <hip/hip_runtime.h>
#include <math.h>

#define NN 2048
#define HID 128
#define HID2 64
#define NP ((NN*(NN-1))/2)   // 2096128

typedef _Float16 f16x8 __attribute__((ext_vector_type(8)));
typedef float    f32x4 __attribute__((ext_vector_type(4)));

// Kernel 1: per node row: h = relu(X@Wt+bt); a = h@W1top + b1; b = h@W1bot.
// Emits Ah (fp16 row-major), Bp (fp16 packed for 16x16x32 B-operand), and
// per-row stats sa/sb from the fp16-ROUNDED values (self-consistent).
__global__ __launch_bounds__(128) void precompute_AB(
    const float* __restrict__ X, const float* __restrict__ Wt, const float* __restrict__ bt,
    const float* __restrict__ W1, const float* __restrict__ b1,
    _Float16* __restrict__ Ah, _Float16* __restrict__ Bp,
    float2* __restrict__ sa, float2* __restrict__ sb)
{
    __shared__ float x_s[HID];
    __shared__ float h_s[HID];
    __shared__ float red[2][4];
    const int row = blockIdx.x;
    const int c = threadIdx.x;
    x_s[c] = X[row*HID + c];
    __syncthreads();
    float hc = bt[c];
    #pragma unroll 8
    for (int k = 0; k < HID; ++k) hc = fmaf(x_s[k], Wt[k*HID + c], hc);
    h_s[c] = fmaxf(hc, 0.f);
    __syncthreads();
    float a = b1[c];
    float bsum = 0.f;
    #pragma unroll 8
    for (int k = 0; k < HID; ++k) {
        float hk = h_s[k];
        a    = fmaf(hk, W1[k*HID + c], a);
        bsum = fmaf(hk, W1[(HID + k)*HID + c], bsum);
    }
    const _Float16 ah = (_Float16)a;
    const _Float16 bh = (_Float16)bsum;
    Ah[row*HID + c] = ah;
    // B-operand packing (16x16x32): frag ks=c>>5, lane = (c>>3&3)*16 + (row&15), e=c&7
    {
        const int ks = c >> 5, g4 = (c >> 3) & 3, e = c & 7;
        Bp[(((size_t)(row >> 4)*4 + ks)*64 + g4*16 + (row & 15))*8 + e] = bh;
    }
    const float ar = (float)ah;
    const float br = (float)bh;
    float r0 = ar, r1 = ar*ar, r2 = br, r3 = br*br;
    #pragma unroll
    for (int m = 1; m <= 32; m <<= 1) {
        r0 += __shfl_xor(r0, m); r1 += __shfl_xor(r1, m);
        r2 += __shfl_xor(r2, m); r3 += __shfl_xor(r3, m);
    }
    if ((c & 63) == 0) {
        red[c >> 6][0] = r0; red[c >> 6][1] = r1; red[c >> 6][2] = r2; red[c >> 6][3] = r3;
    }
    __syncthreads();
    if (c == 0) {
        sa[row] = make_float2(red[0][0] + red[1][0], red[0][1] + red[1][1]);
        sb[row] = make_float2(red[0][2] + red[1][2], red[0][3] + red[1][3]);
    }
}

// Kernel 1b: pack W2 into fp16 A-operand fragments; convert ln_g/ln_b to fp16.
__global__ __launch_bounds__(256) void pack_W2(const float* __restrict__ W2,
                                               const float* __restrict__ ln_g,
                                               const float* __restrict__ ln_b,
                                               _Float16* __restrict__ W2p,
                                               _Float16* __restrict__ ghl,
                                               _Float16* __restrict__ lhl)
{
    const int t = threadIdx.x;
    if (t < HID) { ghl[t] = (_Float16)ln_g[t]; lhl[t] = (_Float16)ln_b[t]; }
    for (int fs = t; fs < 16*64; fs += 256) {
        const int frag = fs >> 6, lane = fs & 63;
        const int ks = frag >> 2, nt = frag & 3;
        const int kbase = ks*32 + (lane >> 4)*8;
        const int col   = nt*16 + (lane & 15);
        #pragma unroll
        for (int e = 0; e < 8; ++e)
            W2p[fs*8 + e] = (_Float16)W2[(kbase + e)*HID2 + col];
    }
}

// Kernel 1c: pair_index is a pure function of indices.
__global__ __launch_bounds__(256) void fill_pi(float* __restrict__ pi)
{
    const int i = blockIdx.x;
    const size_t off = (size_t)i*(NN-1) - (size_t)i*(i-1)/2;
    const int cnt = NN - 1 - i;
    for (int t = threadIdx.x; t < cnt; t += 256) {
        pi[off + t]      = (float)i;
        pi[NP + off + t] = (float)(i + 1 + t);
    }
}

// Kernel 2: 256 threads (4 waves), 4 subs of 16 pairs per wave; fp16 packed
// zn pass (native ext-vector ops -> v_pk_fma_f16); W2 in LDS; b2 folded into
// acc init; B prefetch one sub ahead.
__global__ __launch_bounds__(256, 3) void pairs_mfma(
    const _Float16* __restrict__ Ah, const _Float16* __restrict__ Bp,
    const float2* __restrict__ sa, const float2* __restrict__ sb,
    const _Float16* __restrict__ ghl, const _Float16* __restrict__ lhl,
    const _Float16* __restrict__ W2p, const float* __restrict__ b2,
    const float* __restrict__ W3, const float* __restrict__ b3,
    float* __restrict__ out)
{
    __shared__ f16x8 w2s[16*64];             // 16 KB: all W2 fragments

    {
        const f16x8* __restrict__ W2v = (const f16x8*)W2p;
        #pragma unroll
        for (int t = 0; t < 4; ++t)
            w2s[t*256 + threadIdx.x] = W2v[t*256 + threadIdx.x];
    }

    // decode linear tile id -> (i, jb) over upper-triangular 256x256 tiles
    int t = blockIdx.x;
    int q = 0, base = 0;
    while (q < 7 && t >= base + 256*(8 - q)) { base += 256*(8 - q); ++q; }
    const int idx = t - base;
    const int den = 8 - q;
    const int i  = (q << 8) + idx / den;
    const int jb = q + idx % den;

    __syncthreads();

    const int w    = threadIdx.x >> 6;
    const int lane = threadIdx.x & 63;
    const int jw0  = (jb << 8) + (w << 6);       // this wave's 64 j's
    if (jw0 + 63 < i) return;                    // keep the diag wave alive

    const int p16 = lane & 15;
    const int g4  = lane >> 4;

    // A fragments (fp16) + packed LN params, hoisted
    f16x8 abf[4], gh[4], lh[4];
    #pragma unroll
    for (int ks = 0; ks < 4; ++ks) {
        const int kb = ks*32 + g4*8;
        abf[ks] = *(const f16x8*)(Ah + (size_t)i*HID + kb);
        gh[ks]  = *(const f16x8*)(ghl + kb);
        lh[ks]  = *(const f16x8*)(lhl + kb);
    }
    const float2 sav = sa[i];

    const f16x8* __restrict__ Bpv = (const f16x8*)Bp;

    float parts[4];

    // prefetch sub 0's B fragments
    f16x8 bcur[4], bnxt[4];
    {
        const size_t fb = ((size_t)(jw0 >> 4))*4;
        #pragma unroll
        for (int ks = 0; ks < 4; ++ks) bcur[ks] = Bpv[(fb + ks)*64 + lane];
    }

    #pragma unroll
    for (int s = 0; s < 4; ++s) {
        if (s < 3) {                              // issue next sub's B loads early
            const size_t fbn = ((size_t)((jw0 + (s+1)*16) >> 4))*4;
            #pragma unroll
            for (int ks = 0; ks < 4; ++ks) bnxt[ks] = Bpv[(fbn + ks)*64 + lane];
        }
        const int j16 = jw0 + s*16;

        // dot(A[i], B[j_p]) via broadcast-A MFMA, 4 independent chains
        f32x4 d0 = (f32x4){0.f,0.f,0.f,0.f};
        f32x4 d1 = (f32x4){0.f,0.f,0.f,0.f};
        f32x4 d2 = (f32x4){0.f,0.f,0.f,0.f};
        f32x4 d3 = (f32x4){0.f,0.f,0.f,0.f};
        d0 = __builtin_amdgcn_mfma_f32_16x16x32_f16(abf[0], bcur[0], d0, 0, 0, 0);
        d1 = __builtin_amdgcn_mfma_f32_16x16x32_f16(abf[1], bcur[1], d1, 0, 0, 0);
        d2 = __builtin_amdgcn_mfma_f32_16x16x32_f16(abf[2], bcur[2], d2, 0, 0, 0);
        d3 = __builtin_amdgcn_mfma_f32_16x16x32_f16(abf[3], bcur[3], d3, 0, 0, 0);

        // O(1) LN stats for this lane's pair
        const float2 sbv = sb[j16 + p16];
        const float dd   = (d0[0] + d1[0]) + (d2[0] + d3[0]);
        const float mu   = (sav.x + sbv.x) * (1.f/HID);
        const float ez2  = (sav.y + sbv.y + 2.f*dd) * (1.f/HID);
        const float rstd = rsqrtf(ez2 - mu*mu + 1e-5f);
        const float v    = -mu * rstd;

        const _Float16 rh = (_Float16)rstd;
        const _Float16 vh = (_Float16)v;
        const f16x8 zero8 = {};

        // acc init = b2 (bias folded into GEMM); channels = nt*16 + g4*4 + r
        f32x4 acc[4];
        #pragma unroll
        for (int nt = 0; nt < 4; ++nt) acc[nt] = *(const f32x4*)(b2 + nt*16 + g4*4);

        // zn = max(g*(rstd*z + v) + l, 0) in packed fp16; 16 MFMAs
        #pragma unroll
        for (int ks = 0; ks < 4; ++ks) {
            f16x8 z  = abf[ks] + bcur[ks];
            f16x8 qq = z * rh + vh;
            f16x8 af = __builtin_elementwise_max(gh[ks] * qq + lh[ks], zero8);
            #pragma unroll
            for (int nt = 0; nt < 4; ++nt)
                acc[nt] = __builtin_amdgcn_mfma_f32_16x16x32_f16(w2s[(ks*4 + nt)*64 + lane], af, acc[nt], 0, 0, 0);
        }

        // per-sub reduce: part = relu(acc) . W3 over this lane's 16 channels
        float part = 0.f;
        #pragma unroll
        for (int nt = 0; nt < 4; ++nt) {
            f32x4 w3v = *(const f32x4*)(W3 + nt*16 + g4*4);
            #pragma unroll
            for (int r = 0; r < 4; ++r)
                part = fmaf(fmaxf(acc[nt][r], 0.f), w3v[r], part);
        }
        part += __shfl_xor(part, 16);
        part += __shfl_xor(part, 32);
        parts[s] = part;

        if (s < 3) {
            #pragma unroll
            for (int ks = 0; ks < 4; ++ks) bcur[ks] = bnxt[ks];
        }
    }

    // deferred epilogue, all 64 lanes: lane handles pair j = jw0 + lane
    const int sq = lane >> 4;
    float x = parts[0];
    x = (sq == 1) ? parts[1] : x;
    x = (sq == 2) ? parts[2] : x;
    x = (sq == 3) ? parts[3] : x;

    float* probs = out;
    float* adj   = out + 3*(size_t)NP;
    const int j = jw0 + lane;
    if (j == i) {
        adj[(size_t)i*NN + i] = 0.f;
    } else if (j > i) {
        const float pr = 1.f / (1.f + __expf(-(x + b3[0])));
        const int kpair = i*(NN-1) - (i*(i-1))/2 + (j - i - 1);
        probs[kpair] = pr;
        adj[(size_t)i*NN + j] = pr;
        adj[(size_t)j*NN + i] = pr;
    }
}

extern "C" void kernel_launch(void* const* d_in, const int* in_sizes, int n_in,
                              void* d_out, int out_size, void* d_ws, size_t ws_size,
                              hipStream_t stream) {
    const float* X    = (const float*)d_in[0];
    const float* Wt   = (const float*)d_in[1];
    const float* bt   = (const float*)d_in[2];
    const float* W1   = (const float*)d_in[3];
    const float* b1   = (const float*)d_in[4];
    const float* ln_g = (const float*)d_in[5];
    const float* ln_b = (const float*)d_in[6];
    const float* W2   = (const float*)d_in[7];
    const float* b2   = (const float*)d_in[8];
    const float* W3   = (const float*)d_in[9];
    const float* b3   = (const float*)d_in[10];
    float* out = (float*)d_out;

    float2*    sa  = (float2*)d_ws;                    // 16KB
    float2*    sb  = sa + NN;                          // 16KB
    _Float16*  Ah  = (_Float16*)(sb + NN);             // 512KB
    _Float16*  Bp  = Ah + (size_t)NN * HID;            // 512KB (packed)
    _Float16*  W2p = Bp + (size_t)NN * HID;            // 16KB
    _Float16*  ghl = W2p + 16*64*8;                    // 256B
    _Float16*  lhl = ghl + HID;                        // 256B

    precompute_AB<<<NN, HID, 0, stream>>>(X, Wt, bt, W1, b1, Ah, Bp, sa, sb);
    pack_W2<<<1, 256, 0, stream>>>(W2, ln_g, ln_b, W2p, ghl, lhl);
    fill_pi<<<NN-1, 256, 0, stream>>>(out + NP);

    const int nblk = 256 * 36;
    pairs_mfma<<<nblk, 256, 0, stream>>>(Ah, Bp, sa, sb, ghl, lhl, W2p, b2, W3, b3, out);
}

// Round 13
// 96.123 us; speedup vs baseline: 1.6671x; 1.0603x over previous
//
#include <hip/hip_runtime.h>
#include <math.h>

#define NN 2048
#define HID 128
#define HID2 64
#define NP ((NN*(NN-1))/2)   // 2096128

typedef _Float16 f16x8 __attribute__((ext_vector_type(8)));
typedef float    f32x4 __attribute__((ext_vector_type(4)));
typedef float    f32x2 __attribute__((ext_vector_type(2)));

// Kernel 1: per node row: h = relu(X@Wt+bt); a = h@W1top + b1; b = h@W1bot.
// Emits Ah (fp16 row-major), Bp (fp16 packed for 16x16x32 B-operand), and
// per-row stats sa/sb from the fp16-ROUNDED values (self-consistent).
__global__ __launch_bounds__(128) void precompute_AB(
    const float* __restrict__ X, const float* __restrict__ Wt, const float* __restrict__ bt,
    const float* __restrict__ W1, const float* __restrict__ b1,
    _Float16* __restrict__ Ah, _Float16* __restrict__ Bp,
    float2* __restrict__ sa, float2* __restrict__ sb)
{
    __shared__ float x_s[HID];
    __shared__ float h_s[HID];
    __shared__ float red[2][4];
    const int row = blockIdx.x;
    const int c = threadIdx.x;
    x_s[c] = X[row*HID + c];
    __syncthreads();
    float hc = bt[c];
    #pragma unroll 8
    for (int k = 0; k < HID; ++k) hc = fmaf(x_s[k], Wt[k*HID + c], hc);
    h_s[c] = fmaxf(hc, 0.f);
    __syncthreads();
    float a = b1[c];
    float bsum = 0.f;
    #pragma unroll 8
    for (int k = 0; k < HID; ++k) {
        float hk = h_s[k];
        a    = fmaf(hk, W1[k*HID + c], a);
        bsum = fmaf(hk, W1[(HID + k)*HID + c], bsum);
    }
    const _Float16 ah = (_Float16)a;
    const _Float16 bh = (_Float16)bsum;
    Ah[row*HID + c] = ah;
    // B-operand packing (16x16x32): frag ks=c>>5, lane = (c>>3&3)*16 + (row&15), e=c&7
    {
        const int ks = c >> 5, g4 = (c >> 3) & 3, e = c & 7;
        Bp[(((size_t)(row >> 4)*4 + ks)*64 + g4*16 + (row & 15))*8 + e] = bh;
    }
    const float ar = (float)ah;
    const float br = (float)bh;
    float r0 = ar, r1 = ar*ar, r2 = br, r3 = br*br;
    #pragma unroll
    for (int m = 1; m <= 32; m <<= 1) {
        r0 += __shfl_xor(r0, m); r1 += __shfl_xor(r1, m);
        r2 += __shfl_xor(r2, m); r3 += __shfl_xor(r3, m);
    }
    if ((c & 63) == 0) {
        red[c >> 6][0] = r0; red[c >> 6][1] = r1; red[c >> 6][2] = r2; red[c >> 6][3] = r3;
    }
    __syncthreads();
    if (c == 0) {
        sa[row] = make_float2(red[0][0] + red[1][0], red[0][1] + red[1][1]);
        sb[row] = make_float2(red[0][2] + red[1][2], red[0][3] + red[1][3]);
    }
}

// Kernel 1b: pack W2 into fp16 A-operand fragments; convert ln_g/ln_b to fp16.
__global__ __launch_bounds__(256) void pack_W2(const float* __restrict__ W2,
                                               const float* __restrict__ ln_g,
                                               const float* __restrict__ ln_b,
                                               _Float16* __restrict__ W2p,
                                               _Float16* __restrict__ ghl,
                                               _Float16* __restrict__ lhl)
{
    const int t = threadIdx.x;
    if (t < HID) { ghl[t] = (_Float16)ln_g[t]; lhl[t] = (_Float16)ln_b[t]; }
    for (int fs = t; fs < 16*64; fs += 256) {
        const int frag = fs >> 6, lane = fs & 63;
        const int ks = frag >> 2, nt = frag & 3;
        const int kbase = ks*32 + (lane >> 4)*8;
        const int col   = nt*16 + (lane & 15);
        #pragma unroll
        for (int e = 0; e < 8; ++e)
            W2p[fs*8 + e] = (_Float16)W2[(kbase + e)*HID2 + col];
    }
}

// Kernel 2: 256 threads (4 waves), 4 subs of 16 pairs per wave; fp16 packed
// zn pass; W2 in LDS; b2 folded into acc init; B + dot pipelined one sub
// ahead; packed-f32 epilogue; pair_index written here (fill_pi fused).
__global__ __launch_bounds__(256, 3) void pairs_mfma(
    const _Float16* __restrict__ Ah, const _Float16* __restrict__ Bp,
    const float2* __restrict__ sa, const float2* __restrict__ sb,
    const _Float16* __restrict__ ghl, const _Float16* __restrict__ lhl,
    const _Float16* __restrict__ W2p, const float* __restrict__ b2,
    const float* __restrict__ W3, const float* __restrict__ b3,
    float* __restrict__ out)
{
    __shared__ f16x8 w2s[16*64];             // 16 KB: all W2 fragments

    {
        const f16x8* __restrict__ W2v = (const f16x8*)W2p;
        #pragma unroll
        for (int t = 0; t < 4; ++t)
            w2s[t*256 + threadIdx.x] = W2v[t*256 + threadIdx.x];
    }

    // decode linear tile id -> (i, jb) over upper-triangular 256x256 tiles
    int t = blockIdx.x;
    int q = 0, base = 0;
    while (q < 7 && t >= base + 256*(8 - q)) { base += 256*(8 - q); ++q; }
    const int idx = t - base;
    const int den = 8 - q;
    const int i  = (q << 8) + idx / den;
    const int jb = q + idx % den;

    __syncthreads();

    const int w    = threadIdx.x >> 6;
    const int lane = threadIdx.x & 63;
    const int jw0  = (jb << 8) + (w << 6);       // this wave's 64 j's
    if (jw0 + 63 < i) return;                    // keep the diag wave alive

    const int p16 = lane & 15;
    const int g4  = lane >> 4;

    // A fragments (fp16) + packed LN params, hoisted
    f16x8 abf[4], gh[4], lh[4];
    #pragma unroll
    for (int ks = 0; ks < 4; ++ks) {
        const int kb = ks*32 + g4*8;
        abf[ks] = *(const f16x8*)(Ah + (size_t)i*HID + kb);
        gh[ks]  = *(const f16x8*)(ghl + kb);
        lh[ks]  = *(const f16x8*)(lhl + kb);
    }
    const float2 sav = sa[i];

    const f16x8* __restrict__ Bpv = (const f16x8*)Bp;

    float parts[4];

    // prologue: sub 0's B fragments and dot chains
    f16x8 bcur[4], bnxt[4];
    {
        const size_t fb = ((size_t)(jw0 >> 4))*4;
        #pragma unroll
        for (int ks = 0; ks < 4; ++ks) bcur[ks] = Bpv[(fb + ks)*64 + lane];
    }
    f32x4 dc[4];
    #pragma unroll
    for (int c = 0; c < 4; ++c) {
        dc[c] = (f32x4){0.f,0.f,0.f,0.f};
        dc[c] = __builtin_amdgcn_mfma_f32_16x16x32_f16(abf[c], bcur[c], dc[c], 0, 0, 0);
    }

    #pragma unroll
    for (int s = 0; s < 4; ++s) {
        if (s < 3) {                              // issue next sub's B loads early
            const size_t fbn = ((size_t)((jw0 + (s+1)*16) >> 4))*4;
            #pragma unroll
            for (int ks = 0; ks < 4; ++ks) bnxt[ks] = Bpv[(fbn + ks)*64 + lane];
        }
        const int j16 = jw0 + s*16;

        // O(1) LN stats for this lane's pair (dot was issued last iteration)
        const float2 sbv = sb[j16 + p16];
        const float dd   = (dc[0][0] + dc[1][0]) + (dc[2][0] + dc[3][0]);
        const float mu   = (sav.x + sbv.x) * (1.f/HID);
        const float ez2  = (sav.y + sbv.y + 2.f*dd) * (1.f/HID);
        const float rstd = rsqrtf(ez2 - mu*mu + 1e-5f);
        const float v    = -mu * rstd;

        // next sub's dot chains — overlap with this sub's zn + GEMM MFMAs
        f32x4 dn[4];
        if (s < 3) {
            #pragma unroll
            for (int c = 0; c < 4; ++c) {
                dn[c] = (f32x4){0.f,0.f,0.f,0.f};
                dn[c] = __builtin_amdgcn_mfma_f32_16x16x32_f16(abf[c], bnxt[c], dn[c], 0, 0, 0);
            }
        }

        const _Float16 rh = (_Float16)rstd;
        const _Float16 vh = (_Float16)v;
        const f16x8 zero8 = {};

        // acc init = b2 (bias folded into GEMM); channels = nt*16 + g4*4 + r
        f32x4 acc[4];
        #pragma unroll
        for (int nt = 0; nt < 4; ++nt) acc[nt] = *(const f32x4*)(b2 + nt*16 + g4*4);

        // zn = max(g*(rstd*z + v) + l, 0) in packed fp16; 16 MFMAs
        #pragma unroll
        for (int ks = 0; ks < 4; ++ks) {
            f16x8 z  = abf[ks] + bcur[ks];
            f16x8 qq = z * rh + vh;
            f16x8 af = __builtin_elementwise_max(gh[ks] * qq + lh[ks], zero8);
            #pragma unroll
            for (int nt = 0; nt < 4; ++nt)
                acc[nt] = __builtin_amdgcn_mfma_f32_16x16x32_f16(w2s[(ks*4 + nt)*64 + lane], af, acc[nt], 0, 0, 0);
        }

        // per-sub reduce in packed f32: part = relu(acc) . W3
        f32x2 pv = (f32x2){0.f, 0.f};
        const f32x2 z2 = (f32x2){0.f, 0.f};
        #pragma unroll
        for (int nt = 0; nt < 4; ++nt) {
            const f32x2* w3p = (const f32x2*)(W3 + nt*16 + g4*4);
            f32x2 a0 = (f32x2){acc[nt][0], acc[nt][1]};
            f32x2 a1 = (f32x2){acc[nt][2], acc[nt][3]};
            pv = __builtin_elementwise_max(a0, z2) * w3p[0] + pv;
            pv = __builtin_elementwise_max(a1, z2) * w3p[1] + pv;
        }
        float part = pv[0] + pv[1];
        part += __shfl_xor(part, 16);
        part += __shfl_xor(part, 32);
        parts[s] = part;

        if (s < 3) {
            #pragma unroll
            for (int ks = 0; ks < 4; ++ks) bcur[ks] = bnxt[ks];
            #pragma unroll
            for (int c = 0; c < 4; ++c) dc[c] = dn[c];
        }
    }

    // deferred epilogue, all 64 lanes: lane handles pair j = jw0 + lane
    const int sq = lane >> 4;
    float x = parts[0];
    x = (sq == 1) ? parts[1] : x;
    x = (sq == 2) ? parts[2] : x;
    x = (sq == 3) ? parts[3] : x;

    float* probs = out;
    float* pi    = out + NP;
    float* adj   = out + 3*(size_t)NP;
    const int j = jw0 + lane;
    if (j == i) {
        adj[(size_t)i*NN + i] = 0.f;
    } else if (j > i) {
        const float pr = 1.f / (1.f + __expf(-(x + b3[0])));
        const int kpair = i*(NN-1) - (i*(i-1))/2 + (j - i - 1);
        probs[kpair]    = pr;
        pi[kpair]       = (float)i;
        pi[NP + kpair]  = (float)j;
        adj[(size_t)i*NN + j] = pr;
        adj[(size_t)j*NN + i] = pr;
    }
}

extern "C" void kernel_launch(void* const* d_in, const int* in_sizes, int n_in,
                              void* d_out, int out_size, void* d_ws, size_t ws_size,
                              hipStream_t stream) {
    const float* X    = (const float*)d_in[0];
    const float* Wt   = (const float*)d_in[1];
    const float* bt   = (const float*)d_in[2];
    const float* W1   = (const float*)d_in[3];
    const float* b1   = (const float*)d_in[4];
    const float* ln_g = (const float*)d_in[5];
    const float* ln_b = (const float*)d_in[6];
    const float* W2   = (const float*)d_in[7];
    const float* b2   = (const float*)d_in[8];
    const float* W3   = (const float*)d_in[9];
    const float* b3   = (const float*)d_in[10];
    float* out = (float*)d_out;

    float2*    sa  = (float2*)d_ws;                    // 16KB
    float2*    sb  = sa + NN;                          // 16KB
    _Float16*  Ah  = (_Float16*)(sb + NN);             // 512KB
    _Float16*  Bp  = Ah + (size_t)NN * HID;            // 512KB (packed)
    _Float16*  W2p = Bp + (size_t)NN * HID;            // 16KB
    _Float16*  ghl = W2p + 16*64*8;                    // 256B
    _Float16*  lhl = ghl + HID;                        // 256B

    precompute_AB<<<NN, HID, 0, stream>>>(X, Wt, bt, W1, b1, Ah, Bp, sa, sb);
    pack_W2<<<1, 256, 0, stream>>>(W2, ln_g, ln_b, W2p, ghl, lhl);

    const int nblk = 256 * 36;
    pairs_mfma<<<nblk, 256, 0, stream>>>(Ah, Bp, sa, sb, ghl, lhl, W2p, b2, W3, b3, out);
}